// Round 18
// baseline (120.596 us; speedup 1.0000x reference)
//
#include <hip/hip_runtime.h>

// PointNet 3-NN feature interpolation, v18: single fused KNN kernel.
// knn3_fused: 256 blocks x 1024 threads (16 waves). All waves share the
//             block's 64 queries (1/thread, broadcast form). Wave w scans
//             point slice [w*N/16, (w+1)*N/16). Point broadcast via
//             v_readlane (lane k's registers -> SGPRs): no LDS staging,
//             no per-chunk barriers. Phase 1: tau over first 1024 pts
//             (value-only). Phase 2: filtered d<=tau scan, strict-< insert
//             (ascending stream). Cross-wave lex merge in LDS by wave 0.
//             3 barriers total. Weights written inline.
// interp    : per-(b,d) row staged in LDS, gather+weighted-sum (~5 us).

constexpr float DINF  = 3.4e38f;
constexpr int   ISENT = 0x7fffffff;
constexpr int   NW    = 16;        // waves per block

__device__ __forceinline__ float rlane(float v, int k) {
    return __uint_as_float(__builtin_amdgcn_readlane(__float_as_uint(v), k));
}

// strict-< top-3 insert (per-wave stream ascending-n => lex-equivalent)
__device__ __forceinline__ void insert3b(float& d0, float& d1, float& d2,
                                         int& i0, int& i1, int& i2,
                                         float d, int n) {
    bool c0 = d < d0, c1 = d < d1, c2 = d < d2;
    float nd2 = c1 ? d1 : (c2 ? d : d2);
    int   ni2 = c1 ? i1 : (c2 ? n : i2);
    float nd1 = c0 ? d0 : (c1 ? d : d1);
    int   ni1 = c0 ? i0 : (c1 ? n : i1);
    float nd0 = c0 ? d  : d0;
    int   ni0 = c0 ? n  : i0;
    d0 = nd0; d1 = nd1; d2 = nd2;
    i0 = ni0; i1 = ni1; i2 = ni2;
}

// branchless lexicographic insert (cross-wave merge: exact top_k ties)
__device__ __forceinline__ void ins_lex_nb(float& d0, float& d1, float& d2,
                                           int& i0, int& i1, int& i2,
                                           float d, int n) {
    bool l2 = (d < d2) || (d == d2 && n < i2);
    bool l1 = (d < d1) || (d == d1 && n < i1);
    bool l0 = (d < d0) || (d == d0 && n < i0);
    float nd2 = l1 ? d1 : (l2 ? d : d2);
    int   ni2 = l1 ? i1 : (l2 ? n : i2);
    float nd1 = l0 ? d0 : (l1 ? d : d1);
    int   ni1 = l0 ? i0 : (l1 ? n : i1);
    d0 = l0 ? d : d0;  i0 = l0 ? n : i0;
    d1 = nd1; d2 = nd2; i1 = ni1; i2 = ni2;
}

// value-only top-3 insert (tau)
__device__ __forceinline__ void ins_v(float& d0, float& d1, float& d2, float d) {
    bool c0 = d < d0, c1 = d < d1, c2 = d < d2;
    float n2 = c1 ? d1 : (c2 ? d : d2);
    float n1 = c0 ? d0 : (c1 ? d : d1);
    d0 = c0 ? d : d0; d1 = n1; d2 = n2;
}

__global__ __launch_bounds__(1024, 4)
void knn3_fused(const float* __restrict__ xyz1, const float* __restrict__ xyz2,
                int B, int N, int S,
                int* __restrict__ idx0, int* __restrict__ idx1,
                int* __restrict__ idx2,
                float* __restrict__ w0, float* __restrict__ w1,
                float* __restrict__ w2)
{
#pragma clang fp contract(off)
    __shared__ float fd[NW][64][3];
    __shared__ int   fi[NW][64][3];
    __shared__ float tauL[64];

    const int tid  = threadIdx.x;
    const int w    = tid >> 6;                // 0..15
    const int lane = tid & 63;
    const int tpb  = S / 64;                  // query tiles per batch (32)
    const int b    = blockIdx.x / tpb;        // block-uniform
    const int s    = (blockIdx.x - b * tpb) * 64 + lane;  // same set for all w

    // query registers (redundant across waves; L1-served)
    const float* __restrict__ q2p = xyz2 + (size_t)b * 3 * S;
    const float qx = q2p[s];
    const float qy = q2p[S + s];
    const float qz = q2p[2 * S + s];
    const float qss = (qx * qx + qy * qy) + qz * qz;   // np sum order

    const float* __restrict__ bx = xyz1 + (size_t)b * 3 * N;

    // ---- phase 1: tau over first NW*64 = 1024 points (value-only) ----
    // lane's point: {2x,2y,2z,norm}. 2x exact (pow2); (qx*2x+qy*2y)+qz*2z
    // rounds bit-identically to 2*((qx*x+qy*y)+qz*z); norm np order.
    float t0 = DINF, t1 = DINF, t2 = DINF;
    {
        const int n = w * 64 + lane;
        float x = bx[n], y = bx[N + n], z = bx[2 * N + n];
        float px = x + x, py = y + y, pz = z + z;
        float pw = (x * x + y * y) + z * z;
#pragma unroll 8
        for (int k = 0; k < 64; ++k) {
            float sx = rlane(px, k), sy = rlane(py, k);
            float sz = rlane(pz, k), sw = rlane(pw, k);
            float dot2 = (qx * sx + qy * sy) + qz * sz;
            float d    = (qss + sw) - dot2;
            ins_v(t0, t1, t2, d);
        }
    }
    fd[w][lane][0] = t0; fd[w][lane][1] = t1; fd[w][lane][2] = t2;
    __syncthreads();                                    // barrier 1

    if (w == 0) {
        float a0 = DINF, a1 = DINF, a2 = DINF;
#pragma unroll
        for (int ww = 0; ww < NW; ++ww) {
            ins_v(a0, a1, a2, fd[ww][lane][0]);
            ins_v(a0, a1, a2, fd[ww][lane][1]);
            ins_v(a0, a1, a2, fd[ww][lane][2]);
        }
        tauL[lane] = a2;          // tau >= global d2: exact bound (subset)
    }
    __syncthreads();                                    // barrier 2
    const float tq = tauL[lane];

    // ---- phase 2: wave w scans its slice, filter d<=tau ----
    float d0 = DINF, d1 = DINF, d2 = DINF;
    int   i0 = ISENT, i1 = ISENT, i2 = ISENT;
    const int PW   = N / NW;                  // 512
    const int base = w * PW;
    for (int g = 0; g < PW / 64; ++g) {
        const int n0 = base + g * 64;
        const int n  = n0 + lane;
        float x = bx[n], y = bx[N + n], z = bx[2 * N + n];
        float px = x + x, py = y + y, pz = z + z;
        float pw = (x * x + y * y) + z * z;
#pragma unroll 8
        for (int k = 0; k < 64; ++k) {
            float sx = rlane(px, k), sy = rlane(py, k);
            float sz = rlane(pz, k), sw = rlane(pw, k);
            float dot2 = (qx * sx + qy * sy) + qz * sz;
            float d    = (qss + sw) - dot2;
            if (__builtin_expect(d <= tq, 0))  // keeps tau-ties: exact
                insert3b(d0, d1, d2, i0, i1, i2, d, n0 + k);
        }
    }
    fd[w][lane][0] = d0; fd[w][lane][1] = d1; fd[w][lane][2] = d2;
    fi[w][lane][0] = i0; fi[w][lane][1] = i1; fi[w][lane][2] = i2;
    __syncthreads();                                    // barrier 3

    // ---- final: wave 0 lex-merges 16 wave-partials, writes outputs ----
    if (w == 0) {
        float m0 = DINF, m1 = DINF, m2 = DINF;
        int   j0 = ISENT, j1 = ISENT, j2 = ISENT;
#pragma unroll
        for (int ww = 0; ww < NW; ++ww) {
            ins_lex_nb(m0, m1, m2, j0, j1, j2, fd[ww][lane][0], fi[ww][lane][0]);
            ins_lex_nb(m0, m1, m2, j0, j1, j2, fd[ww][lane][1], fi[ww][lane][1]);
            ins_lex_nb(m0, m1, m2, j0, j1, j2, fd[ww][lane][2], fi[ww][lane][2]);
        }
        const int q = b * S + s;
        float r0 = 1.0f / (m0 + 1e-8f);
        float r1 = 1.0f / (m1 + 1e-8f);
        float r2 = 1.0f / (m2 + 1e-8f);
        float sum = (r0 + r1) + r2;           // np sum order
        idx0[q] = j0; idx1[q] = j1; idx2[q] = j2;
        w0[q] = r0 / sum; w1[q] = r1 / sum; w2[q] = r2 / sum;
    }
}

__global__ __launch_bounds__(256)
void interp_kernel(const float* __restrict__ points1,
                   const int* __restrict__ idx0, const int* __restrict__ idx1,
                   const int* __restrict__ idx2,
                   const float* __restrict__ w0, const float* __restrict__ w1,
                   const float* __restrict__ w2,
                   float* __restrict__ out, int N, int S, int D)
{
#pragma clang fp contract(off)
    __shared__ float row[8192];
    const int bd = blockIdx.x;
    const int b  = bd / D;
    const float* __restrict__ src = points1 + (size_t)bd * N;

    for (int i = threadIdx.x * 4; i < N; i += blockDim.x * 4) {
        *reinterpret_cast<float4*>(&row[i]) =
            *reinterpret_cast<const float4*>(src + i);
    }
    __syncthreads();

    float* __restrict__ dst = out + (size_t)bd * S;
    const int qb = b * S;
    for (int s = threadIdx.x; s < S; s += blockDim.x) {
        int q = qb + s;
        float a = row[idx0[q]] * w0[q];
        float c = row[idx1[q]] * w1[q];
        float e = row[idx2[q]] * w2[q];
        dst[s] = (a + c) + e;                 // np sum order
    }
}

extern "C" void kernel_launch(void* const* d_in, const int* in_sizes, int n_in,
                              void* d_out, int out_size, void* d_ws, size_t ws_size,
                              hipStream_t stream) {
    const float* xyz1    = (const float*)d_in[0];
    const float* xyz2    = (const float*)d_in[1];
    const float* points1 = (const float*)d_in[2];
    float* out = (float*)d_out;

    const int B = 8;
    const int N = in_sizes[0] / (3 * B);
    const int S = in_sizes[1] / (3 * B);
    const int D = in_sizes[2] / (B * N);
    const int BS = B * S;

    int*   idx0 = (int*)d_ws;
    int*   idx1 = idx0 + BS;
    int*   idx2 = idx1 + BS;
    float* w0   = (float*)(idx2 + BS);
    float* w1   = w0 + BS;
    float* w2   = w1 + BS;

    // 256 blocks x 1024 threads: 64 queries/block, 16 waves share them.
    knn3_fused<<<BS / 64, 1024, 0, stream>>>(xyz1, xyz2, B, N, S,
                                             idx0, idx1, idx2, w0, w1, w2);

    interp_kernel<<<B * D, 256, 0, stream>>>(points1, idx0, idx1, idx2,
                                             w0, w1, w2, out, N, S, D);
}